// Round 1
// baseline (256.563 us; speedup 1.0000x reference)
//
#include <hip/hip_runtime.h>
#include <stdint.h>

// Problem constants (fixed by the reference)
#define NN 2048      // nodes
#define DE 16        // embedding dim
#define BB 64        // batch
#define CC 64        // in channels
#define OO 64        // out channels
#define BC 4096      // BB*CC
#define KR 192       // K*CC = 3*64 reduction length

using bf16x8 = __attribute__((ext_vector_type(8))) __bf16;
using f32x4  = __attribute__((ext_vector_type(4))) float;

__device__ __forceinline__ unsigned short f2bf(float f) {
  union { float f; unsigned int u; } v; v.f = f;
  unsigned int u = v.u;
  return (unsigned short)((u + 0x7FFFu + ((u >> 16) & 1u)) >> 16);  // RNE
}
__device__ __forceinline__ float bf2f(unsigned short h) {
  union { unsigned int u; float f; } v; v.u = ((unsigned int)h) << 16;
  return v.f;
}
// async global->LDS, 16B per lane. LDS dst must be wave-uniform base + lane*16.
__device__ __forceinline__ void gll16(const void* g, void* l) {
  __builtin_amdgcn_global_load_lds(
      (const __attribute__((address_space(1))) unsigned int*)g,
      (__attribute__((address_space(3))) unsigned int*)l, 16, 0, 0);
}

// ---------------------------------------------------------------------------
// Kernel 1: pack feat [B,N,C] fp32 -> Fbf node-major [N][B*C] bf16
//                                  -> FbfT        [B*C][N] bf16 (GEMM1 B-op)
// grid (32 n-tiles, 64 b), block 256
__global__ __launch_bounds__(256) void pack_feat(const float* __restrict__ feat,
                                                 unsigned short* __restrict__ Fbf,
                                                 unsigned short* __restrict__ FbfT) {
  __shared__ float tile[64][65];  // +1 pad: conflict-free column reads
  const int b  = blockIdx.y;
  const int n0 = blockIdx.x * 64;
  const int t  = threadIdx.x;
  const int tr = t >> 4, tc4 = (t & 15) * 4;
#pragma unroll
  for (int i = 0; i < 4; ++i) {
    const int r = tr + i * 16;
    const float4 v = *(const float4*)(feat + (size_t)b * (NN * CC) + (size_t)(n0 + r) * CC + tc4);
    tile[r][tc4 + 0] = v.x; tile[r][tc4 + 1] = v.y;
    tile[r][tc4 + 2] = v.z; tile[r][tc4 + 3] = v.w;
  }
  __syncthreads();
  // node-major bf16 (coalesced 8B stores)
#pragma unroll
  for (int i = 0; i < 4; ++i) {
    const int r = tr + i * 16;
    const unsigned int lo = f2bf(tile[r][tc4 + 0]) | ((unsigned int)f2bf(tile[r][tc4 + 1]) << 16);
    const unsigned int hi = f2bf(tile[r][tc4 + 2]) | ((unsigned int)f2bf(tile[r][tc4 + 3]) << 16);
    *(uint2*)(Fbf + (size_t)(n0 + r) * BC + b * CC + tc4) = make_uint2(lo, hi);
  }
  // transposed bf16: lanes cover consecutive n -> 128B contiguous per column
  const int rr = t & 63;
  const int cb = t >> 6;
#pragma unroll
  for (int i = 0; i < 16; ++i) {
    const int c = cb * 16 + i;
    FbfT[(size_t)(b * CC + c) * NN + n0 + rr] = f2bf(tile[rr][c]);
  }
}

// ---------------------------------------------------------------------------
// Kernel 2: adjacency row softmax(relu(E E^T)) -> Abf bf16 [N][N]; Bias = E@bias_pool
// grid 2048 (one row), block 256
__global__ __launch_bounds__(256) void adj_softmax(const float* __restrict__ E,
                                                   const float* __restrict__ bias_pool,
                                                   unsigned short* __restrict__ Abf,
                                                   float* __restrict__ Bias) {
  const int n = blockIdx.x, t = threadIdx.x;
  __shared__ float en[16];
  __shared__ float red[8];
  if (t < 16) en[t] = E[n * 16 + t];
  __syncthreads();
  float er[16];
#pragma unroll
  for (int d = 0; d < 16; ++d) er[d] = en[d];

  float v[8];
  float mx = 0.0f;  // relu floor: max >= 0 always
#pragma unroll
  for (int i = 0; i < 8; ++i) {
    const int m = t + i * 256;
    const float4* Em = (const float4*)(E + m * 16);
    const float4 a = Em[0], b = Em[1], c = Em[2], d = Em[3];
    float dot = er[0] * a.x + er[1] * a.y + er[2] * a.z + er[3] * a.w
              + er[4] * b.x + er[5] * b.y + er[6] * b.z + er[7] * b.w
              + er[8] * c.x + er[9] * c.y + er[10] * c.z + er[11] * c.w
              + er[12] * d.x + er[13] * d.y + er[14] * d.z + er[15] * d.w;
    v[i] = fmaxf(dot, 0.0f);
    mx = fmaxf(mx, v[i]);
  }
#pragma unroll
  for (int off = 32; off > 0; off >>= 1) mx = fmaxf(mx, __shfl_xor(mx, off, 64));
  const int wave = t >> 6, lane = t & 63;
  if (lane == 0) red[wave] = mx;
  __syncthreads();
  mx = fmaxf(fmaxf(red[0], red[1]), fmaxf(red[2], red[3]));
  float s = 0.0f;
#pragma unroll
  for (int i = 0; i < 8; ++i) { v[i] = __expf(v[i] - mx); s += v[i]; }
#pragma unroll
  for (int off = 32; off > 0; off >>= 1) s += __shfl_xor(s, off, 64);
  if (lane == 0) red[4 + wave] = s;
  __syncthreads();
  s = red[4] + red[5] + red[6] + red[7];
  const float inv = 1.0f / s;
#pragma unroll
  for (int i = 0; i < 8; ++i)
    Abf[(size_t)n * NN + t + i * 256] = f2bf(v[i] * inv);
  if (t < 64) {
    float bs = 0.0f;
#pragma unroll
    for (int d = 0; d < 16; ++d) bs += er[d] * bias_pool[d * 64 + t];
    Bias[n * 64 + t] = bs;
  }
}

// ---------------------------------------------------------------------------
// Kernel 3: per-node weights W[n][r][o] = sum_d E[n,d]*wp[d][r][o], r=k*64+i,
// stored K8-blocked: Wg[n][(r>>3)][o][r&7] bf16 -> final kernel B-frags are
// contiguous ds_read_b128 with only 2-way (free) bank conflicts.
// grid (24 r-blocks, 32 n-tiles of 64), block 256
__global__ __launch_bounds__(256) void make_w(const float* __restrict__ wp,
                                              const float* __restrict__ E,
                                              unsigned short* __restrict__ Wg) {
  __shared__ float wl[16][8][64];  // 32 KB: wp slice [d][rl][o]
  __shared__ float el[64][16];     // 4 KB: E tile
  const int rq = blockIdx.x;          // r = rq*8 + rl
  const int n0 = blockIdx.y * 64;
  const int t  = threadIdx.x;
  for (int p = t; p < 2048; p += 256) {
    const int idx = p * 4;
    const int d = idx >> 9, rem = idx & 511, rl = rem >> 6, o = rem & 63;
    *(float4*)&wl[d][rl][o] = *(const float4*)(wp + (size_t)d * (KR * OO) + (size_t)(rq * 8 + rl) * 64 + o);
  }
  {
    const int nl = t >> 2, d4 = (t & 3) * 4;
    *(float4*)&el[nl][d4] = *(const float4*)(E + (size_t)(n0 + nl) * 16 + d4);
  }
  __syncthreads();
  const int o = t & 63, ng = t >> 6;
  for (int ii = 0; ii < 16; ++ii) {
    const int nl = ng * 16 + ii;  // whole wave shares nl -> el broadcast reads
    float a[8] = {0, 0, 0, 0, 0, 0, 0, 0};
#pragma unroll
    for (int d = 0; d < 16; ++d) {
      const float e = el[nl][d];
#pragma unroll
      for (int rl = 0; rl < 8; ++rl) a[rl] = fmaf(e, wl[d][rl][o], a[rl]);
    }
    const unsigned int w0 = f2bf(a[0]) | ((unsigned int)f2bf(a[1]) << 16);
    const unsigned int w1 = f2bf(a[2]) | ((unsigned int)f2bf(a[3]) << 16);
    const unsigned int w2 = f2bf(a[4]) | ((unsigned int)f2bf(a[5]) << 16);
    const unsigned int w3 = f2bf(a[6]) | ((unsigned int)f2bf(a[7]) << 16);
    *(uint4*)(Wg + (size_t)(n0 + nl) * (KR * OO) + (size_t)rq * 512 + o * 8) =
        make_uint4(w0, w1, w2, w3);
  }
}

// ---------------------------------------------------------------------------
// Kernel 4: m97-style 128x128x32 bf16 MFMA GEMM, C = A[2048,2048] @ B, with B
// given transposed (Bt[j][k], K-contiguous). EPI=1: store G1 node-major +
// G1T transposed (next GEMM's B-op). EPI=2: store G2 = 2*acc - F node-major.
template <int EPI>
__global__ __launch_bounds__(256, 2) void gemm128(const unsigned short* __restrict__ A,
                                                  const unsigned short* __restrict__ Bt,
                                                  unsigned short* __restrict__ Cnm,
                                                  unsigned short* __restrict__ Ct,
                                                  const unsigned short* __restrict__ F) {
  __shared__ alignas(16) unsigned short As[128 * 32];
  __shared__ alignas(16) unsigned short Bs[128 * 32];
  const int t = threadIdx.x;
  const int bm = blockIdx.y * 128, bn = blockIdx.x * 128;
  const int wave = t >> 6, lane = t & 63;
  const int wm = (wave >> 1) * 64, wn = (wave & 1) * 64;

  f32x4 acc[4][4];
#pragma unroll
  for (int r = 0; r < 4; ++r)
#pragma unroll
    for (int c = 0; c < 4; ++c) acc[r][c] = (f32x4){0.f, 0.f, 0.f, 0.f};

  const int e0 = t * 8, e1 = (t + 256) * 8;           // bf16 elem offsets in tile
  const int r0 = e0 >> 5, c0 = e0 & 31;
  const int r1 = e1 >> 5, c1 = e1 & 31;
  const unsigned short* A0 = A + (size_t)(bm + r0) * NN + c0;
  const unsigned short* A1 = A + (size_t)(bm + r1) * NN + c1;
  const unsigned short* B0 = Bt + (size_t)(bn + r0) * NN + c0;
  const unsigned short* B1 = Bt + (size_t)(bn + r1) * NN + c1;
  const int aoff = (wm + (lane & 15)) * 32 + (lane >> 4) * 8;
  const int boff = (wn + (lane & 15)) * 32 + (lane >> 4) * 8;

  for (int k0 = 0; k0 < NN; k0 += 32) {
    __syncthreads();  // prior-iter LDS reads done before overwrite
    gll16(A0 + k0, &As[e0]);
    gll16(A1 + k0, &As[e1]);
    gll16(B0 + k0, &Bs[e0]);
    gll16(B1 + k0, &Bs[e1]);
    __syncthreads();  // compiler drains vmcnt before s_barrier
    bf16x8 af[4], bfr[4];
#pragma unroll
    for (int r = 0; r < 4; ++r) af[r] = *(const bf16x8*)&As[aoff + r * 512];
#pragma unroll
    for (int c = 0; c < 4; ++c) bfr[c] = *(const bf16x8*)&Bs[boff + c * 512];
#pragma unroll
    for (int r = 0; r < 4; ++r)
#pragma unroll
      for (int c = 0; c < 4; ++c)
        acc[r][c] = __builtin_amdgcn_mfma_f32_16x16x32_bf16(af[r], bfr[c], acc[r][c], 0, 0, 0);
  }

  const int colL = lane & 15, rowL = (lane >> 4) * 4;  // C/D: col=lane&15, row=quad*4+i
#pragma unroll
  for (int r = 0; r < 4; ++r) {
#pragma unroll
    for (int c = 0; c < 4; ++c) {
      const int gm = bm + wm + r * 16 + rowL;
      const int gn = bn + wn + c * 16 + colL;
      const f32x4 a = acc[r][c];
      if (EPI == 1) {
#pragma unroll
        for (int i = 0; i < 4; ++i)
          Cnm[(size_t)(gm + i) * BC + gn] = f2bf(a[i]);
        const unsigned int lo = f2bf(a[0]) | ((unsigned int)f2bf(a[1]) << 16);
        const unsigned int hi = f2bf(a[2]) | ((unsigned int)f2bf(a[3]) << 16);
        *(uint2*)(Ct + (size_t)gn * NN + gm) = make_uint2(lo, hi);  // gm%4==0 -> 8B aligned
      } else {
#pragma unroll
        for (int i = 0; i < 4; ++i) {
          const float g = 2.0f * a[i] - bf2f(F[(size_t)(gm + i) * BC + gn]);
          Cnm[(size_t)(gm + i) * BC + gn] = f2bf(g);
        }
      }
    }
  }
}

// ---------------------------------------------------------------------------
// Kernel 5: per-node GEMM out[b,n,o] = X_n[64,192] @ W_n[192,64] + bias[n,o]
// X_n rows: [F | G1 | G2] at node n. One block per node, 4 waves, 16x16x32 MFMA.
__global__ __launch_bounds__(256) void final_gemm(const unsigned short* __restrict__ Fbf,
                                                  const unsigned short* __restrict__ G1,
                                                  const unsigned short* __restrict__ G2,
                                                  const unsigned short* __restrict__ Wg,
                                                  const float* __restrict__ Bias,
                                                  float* __restrict__ out) {
  __shared__ alignas(16) unsigned short Xl[64 * 200];  // stride 200: 2-way (free) conflicts
  __shared__ alignas(16) unsigned short Wl[KR * OO];   // K8-blocked, linear copy
  const int n = blockIdx.x, t = threadIdx.x;
  const unsigned short* srcs[3] = {Fbf + (size_t)n * BC, G1 + (size_t)n * BC, G2 + (size_t)n * BC};
#pragma unroll
  for (int kk = 0; kk < 3; ++kk) {
    const uint4* s = (const uint4*)srcs[kk];
    for (int p = t; p < 512; p += 256) {
      const uint4 v = s[p];
      const int j = p * 8, b = j >> 6, i = j & 63;
      *(uint4*)&Xl[b * 200 + kk * 64 + i] = v;
    }
  }
  {
    const uint4* s = (const uint4*)(Wg + (size_t)n * (KR * OO));
    uint4* d = (uint4*)Wl;
    for (int p = t; p < 1536; p += 256) d[p] = s[p];
  }
  __syncthreads();

  const int wave = t >> 6, lane = t & 63;
  const int q = lane >> 4;
  const int brow = wave * 16 + (lane & 15);
  f32x4 acc[4];
#pragma unroll
  for (int c = 0; c < 4; ++c) acc[c] = (f32x4){0.f, 0.f, 0.f, 0.f};
#pragma unroll
  for (int kq = 0; kq < 6; ++kq) {
    const bf16x8 a = *(const bf16x8*)&Xl[brow * 200 + kq * 32 + q * 8];
#pragma unroll
    for (int c = 0; c < 4; ++c) {
      const bf16x8 b = *(const bf16x8*)&Wl[(kq * 4 + q) * 512 + (c * 16 + (lane & 15)) * 8];
      acc[c] = __builtin_amdgcn_mfma_f32_16x16x32_bf16(a, b, acc[c], 0, 0, 0);
    }
  }
  const int col = lane & 15, rbase = wave * 16 + q * 4;
#pragma unroll
  for (int c = 0; c < 4; ++c) {
    const int o = c * 16 + col;
    const float bs = Bias[n * 64 + o];
#pragma unroll
    for (int i = 0; i < 4; ++i)
      out[(size_t)(rbase + i) * (NN * OO) + (size_t)n * OO + o] = acc[c][i] + bs;
  }
}

// ---------------------------------------------------------------------------
extern "C" void kernel_launch(void* const* d_in, const int* in_sizes, int n_in,
                              void* d_out, int out_size, void* d_ws, size_t ws_size,
                              hipStream_t stream) {
  const float* E    = (const float*)d_in[0];  // [2048,16]
  const float* feat = (const float*)d_in[1];  // [64,2048,64]
  const float* wp   = (const float*)d_in[2];  // [16,3,64,64]
  const float* bp   = (const float*)d_in[3];  // [16,64]
  float* out = (float*)d_out;

  char* ws = (char*)d_ws;
  size_t off = 0;
  auto alloc = [&](size_t bytes) -> void* {
    void* p = ws + off;
    off += (bytes + 255) & ~(size_t)255;
    return p;
  };
  unsigned short* Abf  = (unsigned short*)alloc((size_t)NN * NN * 2);   //  8 MB
  unsigned short* FbfT = (unsigned short*)alloc((size_t)BC * NN * 2);   // 16 MB (reused as G2)
  unsigned short* Fbf  = (unsigned short*)alloc((size_t)NN * BC * 2);   // 16 MB
  unsigned short* G1   = (unsigned short*)alloc((size_t)NN * BC * 2);   // 16 MB
  unsigned short* G1T  = (unsigned short*)alloc((size_t)BC * NN * 2);   // 16 MB
  unsigned short* Wg   = (unsigned short*)alloc((size_t)NN * KR * OO * 2); // 48 MB
  float* Bias          = (float*)alloc((size_t)NN * OO * 4);            // 0.5 MB
  unsigned short* G2   = FbfT;  // FbfT dead after GEMM1; GEMM2 reads G1T/Abf/Fbf only

  pack_feat<<<dim3(32, 64), 256, 0, stream>>>(feat, Fbf, FbfT);
  adj_softmax<<<dim3(2048), 256, 0, stream>>>(E, bp, Abf, Bias);
  make_w<<<dim3(24, 32), 256, 0, stream>>>(wp, E, Wg);
  gemm128<1><<<dim3(32, 16), 256, 0, stream>>>(Abf, FbfT, G1, G1T, nullptr);
  gemm128<2><<<dim3(32, 16), 256, 0, stream>>>(Abf, G1T, G2, nullptr, Fbf);
  final_gemm<<<dim3(2048), 256, 0, stream>>>(Fbf, G1, G2, Wg, Bias, out);
}

// Round 2
// 239.709 us; speedup vs baseline: 1.0703x; 1.0703x over previous
//
#include <hip/hip_runtime.h>
#include <stdint.h>

// Problem constants (fixed by the reference)
#define NN 2048      // nodes
#define DE 16        // embedding dim
#define BB 64        // batch
#define CC 64        // in channels
#define OO 64        // out channels
#define BC 4096      // BB*CC
#define KR 192       // K*CC = 3*64 reduction length

using bf16x8 = __attribute__((ext_vector_type(8))) __bf16;
using f32x4  = __attribute__((ext_vector_type(4))) float;

__device__ __forceinline__ unsigned short f2bf(float f) {
  union { float f; unsigned int u; } v; v.f = f;
  unsigned int u = v.u;
  return (unsigned short)((u + 0x7FFFu + ((u >> 16) & 1u)) >> 16);  // RNE
}
__device__ __forceinline__ float bf2f(unsigned short h) {
  union { unsigned int u; float f; } v; v.u = ((unsigned int)h) << 16;
  return v.f;
}
// async global->LDS, 16B per lane. LDS dst is wave-uniform base + lane*16.
__device__ __forceinline__ void gll16(const void* g, void* l) {
  __builtin_amdgcn_global_load_lds(
      (const __attribute__((address_space(1))) unsigned int*)g,
      (__attribute__((address_space(3))) unsigned int*)l, 16, 0, 0);
}

// ---------------------------------------------------------------------------
// Kernel 1 ("prep"): three independent preprocessing jobs merged into one
// dispatch so they fill the GPU concurrently instead of serializing.
//   blocks [0,2048):    pack feat [B,N,C] fp32 -> Fbf [N][B*C] bf16 + FbfT [B*C][N]
//   blocks [2048,4096): adjacency row softmax(relu(E E^T)) -> Abf; Bias = E@bp
//   blocks [4096,4480): make_w v2 — W[n][r][o] = sum_d E[n,d] wp[d][r][o],
//                       wp slice register-cached (64 f32/thread), E row scalar
//                       via readfirstlane (s_load + sgpr-FMA), K8-block layout.
__global__ __launch_bounds__(256) void prep(const float* __restrict__ feat,
                                            const float* __restrict__ E,
                                            const float* __restrict__ wp,
                                            const float* __restrict__ bp,
                                            unsigned short* __restrict__ Fbf,
                                            unsigned short* __restrict__ FbfT,
                                            unsigned short* __restrict__ Abf,
                                            float* __restrict__ Bias,
                                            unsigned short* __restrict__ Wg) {
  __shared__ float smem[64 * 65];  // 16.6 KB, reused per branch
  const int id = blockIdx.x;
  const int t  = threadIdx.x;

  if (id < 2048) {
    // ---- pack_feat: b = id>>5, n-tile = (id&31)*64 ----
    float (*tile)[65] = (float (*)[65])smem;  // +1 pad: conflict-free col reads
    const int b  = id >> 5;
    const int n0 = (id & 31) * 64;
    const int tr = t >> 4, tc4 = (t & 15) * 4;
#pragma unroll
    for (int i = 0; i < 4; ++i) {
      const int r = tr + i * 16;
      const float4 v = *(const float4*)(feat + (size_t)b * (NN * CC) + (size_t)(n0 + r) * CC + tc4);
      tile[r][tc4 + 0] = v.x; tile[r][tc4 + 1] = v.y;
      tile[r][tc4 + 2] = v.z; tile[r][tc4 + 3] = v.w;
    }
    __syncthreads();
#pragma unroll
    for (int i = 0; i < 4; ++i) {
      const int r = tr + i * 16;
      const unsigned int lo = f2bf(tile[r][tc4 + 0]) | ((unsigned int)f2bf(tile[r][tc4 + 1]) << 16);
      const unsigned int hi = f2bf(tile[r][tc4 + 2]) | ((unsigned int)f2bf(tile[r][tc4 + 3]) << 16);
      *(uint2*)(Fbf + (size_t)(n0 + r) * BC + b * CC + tc4) = make_uint2(lo, hi);
    }
    const int rr = t & 63;
    const int cb = t >> 6;
#pragma unroll
    for (int i = 0; i < 16; ++i) {
      const int c = cb * 16 + i;
      FbfT[(size_t)(b * CC + c) * NN + n0 + rr] = f2bf(tile[rr][c]);
    }
  } else if (id < 4096) {
    // ---- adj_softmax: one row per block ----
    const int n = id - 2048;
    float* en  = smem;       // [16]
    float* red = smem + 16;  // [8]
    if (t < 16) en[t] = E[n * 16 + t];
    __syncthreads();
    float er[16];
#pragma unroll
    for (int d = 0; d < 16; ++d) er[d] = en[d];

    float v[8];
    float mx = 0.0f;  // relu floor: max >= 0 always
#pragma unroll
    for (int i = 0; i < 8; ++i) {
      const int m = t + i * 256;
      const float4* Em = (const float4*)(E + m * 16);
      const float4 a = Em[0], b = Em[1], c = Em[2], d = Em[3];
      float dot = er[0] * a.x + er[1] * a.y + er[2] * a.z + er[3] * a.w
                + er[4] * b.x + er[5] * b.y + er[6] * b.z + er[7] * b.w
                + er[8] * c.x + er[9] * c.y + er[10] * c.z + er[11] * c.w
                + er[12] * d.x + er[13] * d.y + er[14] * d.z + er[15] * d.w;
      v[i] = fmaxf(dot, 0.0f);
      mx = fmaxf(mx, v[i]);
    }
#pragma unroll
    for (int off = 32; off > 0; off >>= 1) mx = fmaxf(mx, __shfl_xor(mx, off, 64));
    const int wave = t >> 6, lane = t & 63;
    if (lane == 0) red[wave] = mx;
    __syncthreads();
    mx = fmaxf(fmaxf(red[0], red[1]), fmaxf(red[2], red[3]));
    float s = 0.0f;
#pragma unroll
    for (int i = 0; i < 8; ++i) { v[i] = __expf(v[i] - mx); s += v[i]; }
#pragma unroll
    for (int off = 32; off > 0; off >>= 1) s += __shfl_xor(s, off, 64);
    if (lane == 0) red[4 + wave] = s;
    __syncthreads();
    s = red[4] + red[5] + red[6] + red[7];
    const float inv = 1.0f / s;
#pragma unroll
    for (int i = 0; i < 8; ++i)
      Abf[(size_t)n * NN + t + i * 256] = f2bf(v[i] * inv);
    if (t < 64) {
      float bs = 0.0f;
#pragma unroll
      for (int d = 0; d < 16; ++d) bs += er[d] * bp[d * 64 + t];
      Bias[n * 64 + t] = bs;
    }
  } else {
    // ---- make_w v2: grid 24 rq x 16 n-chunks ----
    const int wid = id - 4096;
    const int rq = wid % 24;        // r-block: rows rq*8 .. rq*8+7
    const int nc = wid / 24;        // n-chunk of 128
    const int o  = t & 63;
    const int rh = (t >> 6) & 1;    // rl half: rows rh*4 .. rh*4+3
    const int g  = t >> 7;          // n-subgroup (wave-uniform)
    // register-cache wp[d][rq*8+rh*4+j][o], 16 d x 4 j = 64 fp32
    float w[16][4];
#pragma unroll
    for (int d = 0; d < 16; ++d)
#pragma unroll
      for (int j = 0; j < 4; ++j)
        w[d][j] = wp[(size_t)d * (KR * OO) + (size_t)(rq * 8 + rh * 4 + j) * 64 + o];
    const int nbase = nc * 128 + g * 64;
    for (int i = 0; i < 64; ++i) {
      const int ns = __builtin_amdgcn_readfirstlane(nbase + i);  // wave-uniform -> s_load
      const float* ep = E + ns * 16;
      float a0 = 0.f, a1 = 0.f, a2 = 0.f, a3 = 0.f;
#pragma unroll
      for (int d = 0; d < 16; ++d) {
        const float e = ep[d];
        a0 = fmaf(e, w[d][0], a0);
        a1 = fmaf(e, w[d][1], a1);
        a2 = fmaf(e, w[d][2], a2);
        a3 = fmaf(e, w[d][3], a3);
      }
      const unsigned int lo = f2bf(a0) | ((unsigned int)f2bf(a1) << 16);
      const unsigned int hi = f2bf(a2) | ((unsigned int)f2bf(a3) << 16);
      *(uint2*)(Wg + (size_t)ns * (KR * OO) + rq * 512 + o * 8 + rh * 4) = make_uint2(lo, hi);
    }
  }
}

// ---------------------------------------------------------------------------
// Kernel 2: m97-style 128x128x32 bf16 MFMA GEMM, C = A[2048,2048] @ B, with B
// given transposed (Bt[j][k], K-contiguous). LDS chunks XOR-swizzled
// (qc' = qc ^ ((row>>1)&3)) so ds_read_b128 fragments hit all 8 chunk-aligned
// bank positions with 2 lanes each (free) instead of 2 positions x 8 (4x stall).
// Swizzle is applied on the *global source column* since global_load_lds pins
// LDS placement to lane*16.
// EPI=1: store G1 node-major + G1T transposed. EPI=2: store G2 = 2*acc - F.
template <int EPI>
__global__ __launch_bounds__(256, 2) void gemm128(const unsigned short* __restrict__ A,
                                                  const unsigned short* __restrict__ Bt,
                                                  unsigned short* __restrict__ Cnm,
                                                  unsigned short* __restrict__ Ct,
                                                  const unsigned short* __restrict__ F) {
  __shared__ alignas(16) unsigned short As[128 * 32];
  __shared__ alignas(16) unsigned short Bs[128 * 32];
  const int t = threadIdx.x;
  const int bm = blockIdx.y * 128, bn = blockIdx.x * 128;
  const int wave = t >> 6, lane = t & 63;
  const int wm = (wave >> 1) * 64, wn = (wave & 1) * 64;

  f32x4 acc[4][4];
#pragma unroll
  for (int r = 0; r < 4; ++r)
#pragma unroll
    for (int c = 0; c < 4; ++c) acc[r][c] = (f32x4){0.f, 0.f, 0.f, 0.f};

  // staging: thread t fills LDS chunks t and t+256 (16B each).
  // chunk j -> tile row j>>2, phys qc j&3; phys qc holds logical (qc ^ (row>>1)&3)
  const int r0 = t >> 2;                                   // tile row 0..63
  const int csw = (((t & 3) ^ ((r0 >> 1) & 3)) * 8);       // swizzled col (elems)
  const unsigned short* A0 = A + (size_t)(bm + r0) * NN + csw;
  const unsigned short* A1 = A + (size_t)(bm + r0 + 64) * NN + csw;  // (row+64)>>1 &3 identical
  const unsigned short* B0 = Bt + (size_t)(bn + r0) * NN + csw;
  const unsigned short* B1 = Bt + (size_t)(bn + r0 + 64) * NN + csw;
  const int e0 = t * 8, e1 = (t + 256) * 8;

  // fragment read offsets: logical k-group q lives at phys chunk q ^ s(row)
  const int li = lane & 15, q = lane >> 4, sw = (li >> 1) & 3;
  const int aoff = (wm + li) * 32 + ((q ^ sw) * 8);
  const int boff = (wn + li) * 32 + ((q ^ sw) * 8);

  for (int k0 = 0; k0 < NN; k0 += 32) {
    __syncthreads();  // prior-iter LDS reads done before overwrite
    gll16(A0 + k0, &As[e0]);
    gll16(A1 + k0, &As[e1]);
    gll16(B0 + k0, &Bs[e0]);
    gll16(B1 + k0, &Bs[e1]);
    __syncthreads();  // compiler drains vmcnt before s_barrier
    bf16x8 af[4], bfr[4];
#pragma unroll
    for (int r = 0; r < 4; ++r) af[r] = *(const bf16x8*)&As[aoff + r * 512];
#pragma unroll
    for (int c = 0; c < 4; ++c) bfr[c] = *(const bf16x8*)&Bs[boff + c * 512];
#pragma unroll
    for (int r = 0; r < 4; ++r)
#pragma unroll
      for (int c = 0; c < 4; ++c)
        acc[r][c] = __builtin_amdgcn_mfma_f32_16x16x32_bf16(af[r], bfr[c], acc[r][c], 0, 0, 0);
  }

  const int colL = lane & 15, rowL = (lane >> 4) * 4;  // C/D: col=lane&15, row=quad*4+i
#pragma unroll
  for (int r = 0; r < 4; ++r) {
#pragma unroll
    for (int c = 0; c < 4; ++c) {
      const int gm = bm + wm + r * 16 + rowL;
      const int gn = bn + wn + c * 16 + colL;
      const f32x4 a = acc[r][c];
      if (EPI == 1) {
#pragma unroll
        for (int i = 0; i < 4; ++i)
          Cnm[(size_t)(gm + i) * BC + gn] = f2bf(a[i]);
        const unsigned int lo = f2bf(a[0]) | ((unsigned int)f2bf(a[1]) << 16);
        const unsigned int hi = f2bf(a[2]) | ((unsigned int)f2bf(a[3]) << 16);
        *(uint2*)(Ct + (size_t)gn * NN + gm) = make_uint2(lo, hi);  // gm%4==0 -> 8B aligned
      } else {
#pragma unroll
        for (int i = 0; i < 4; ++i) {
          const float g = 2.0f * a[i] - bf2f(F[(size_t)(gm + i) * BC + gn]);
          Cnm[(size_t)(gm + i) * BC + gn] = f2bf(g);
        }
      }
    }
  }
}

// ---------------------------------------------------------------------------
// Kernel 3: per-node GEMM out[b,n,o] = X_n[64,192] @ W_n[192,64] + bias[n,o]
// X_n rows: [F | G1 | G2] at node n. One block per node, 4 waves, 16x16x32 MFMA.
__global__ __launch_bounds__(256) void final_gemm(const unsigned short* __restrict__ Fbf,
                                                  const unsigned short* __restrict__ G1,
                                                  const unsigned short* __restrict__ G2,
                                                  const unsigned short* __restrict__ Wg,
                                                  const float* __restrict__ Bias,
                                                  float* __restrict__ out) {
  __shared__ alignas(16) unsigned short Xl[64 * 200];  // stride 200: 2-way (free) conflicts
  __shared__ alignas(16) unsigned short Wl[KR * OO];   // K8-blocked, linear copy
  const int n = blockIdx.x, t = threadIdx.x;
  const unsigned short* srcs[3] = {Fbf + (size_t)n * BC, G1 + (size_t)n * BC, G2 + (size_t)n * BC};
#pragma unroll
  for (int kk = 0; kk < 3; ++kk) {
    const uint4* s = (const uint4*)srcs[kk];
    for (int p = t; p < 512; p += 256) {
      const uint4 v = s[p];
      const int j = p * 8, b = j >> 6, i = j & 63;
      *(uint4*)&Xl[b * 200 + kk * 64 + i] = v;
    }
  }
  {
    const uint4* s = (const uint4*)(Wg + (size_t)n * (KR * OO));
    uint4* d = (uint4*)Wl;
    for (int p = t; p < 1536; p += 256) d[p] = s[p];
  }
  __syncthreads();

  const int wave = t >> 6, lane = t & 63;
  const int q = lane >> 4;
  const int brow = wave * 16 + (lane & 15);
  f32x4 acc[4];
#pragma unroll
  for (int c = 0; c < 4; ++c) acc[c] = (f32x4){0.f, 0.f, 0.f, 0.f};
#pragma unroll
  for (int kq = 0; kq < 6; ++kq) {
    const bf16x8 a = *(const bf16x8*)&Xl[brow * 200 + kq * 32 + q * 8];
#pragma unroll
    for (int c = 0; c < 4; ++c) {
      const bf16x8 b = *(const bf16x8*)&Wl[(kq * 4 + q) * 512 + (c * 16 + (lane & 15)) * 8];
      acc[c] = __builtin_amdgcn_mfma_f32_16x16x32_bf16(a, b, acc[c], 0, 0, 0);
    }
  }
  const int col = lane & 15, rbase = wave * 16 + q * 4;
#pragma unroll
  for (int c = 0; c < 4; ++c) {
    const int o = c * 16 + col;
    const float bs = Bias[n * 64 + o];
#pragma unroll
    for (int i = 0; i < 4; ++i)
      out[(size_t)(rbase + i) * (NN * OO) + (size_t)n * OO + o] = acc[c][i] + bs;
  }
}

// ---------------------------------------------------------------------------
extern "C" void kernel_launch(void* const* d_in, const int* in_sizes, int n_in,
                              void* d_out, int out_size, void* d_ws, size_t ws_size,
                              hipStream_t stream) {
  const float* E    = (const float*)d_in[0];  // [2048,16]
  const float* feat = (const float*)d_in[1];  // [64,2048,64]
  const float* wp   = (const float*)d_in[2];  // [16,3,64,64]
  const float* bp   = (const float*)d_in[3];  // [16,64]
  float* out = (float*)d_out;

  char* ws = (char*)d_ws;
  size_t off = 0;
  auto alloc = [&](size_t bytes) -> void* {
    void* p = ws + off;
    off += (bytes + 255) & ~(size_t)255;
    return p;
  };
  unsigned short* Abf  = (unsigned short*)alloc((size_t)NN * NN * 2);   //  8 MB
  unsigned short* FbfT = (unsigned short*)alloc((size_t)BC * NN * 2);   // 16 MB (reused as G2)
  unsigned short* Fbf  = (unsigned short*)alloc((size_t)NN * BC * 2);   // 16 MB
  unsigned short* G1   = (unsigned short*)alloc((size_t)NN * BC * 2);   // 16 MB
  unsigned short* G1T  = (unsigned short*)alloc((size_t)BC * NN * 2);   // 16 MB
  unsigned short* Wg   = (unsigned short*)alloc((size_t)NN * KR * OO * 2); // 48 MB
  float* Bias          = (float*)alloc((size_t)NN * OO * 4);            // 0.5 MB
  unsigned short* G2   = FbfT;  // FbfT dead after GEMM1; GEMM2 reads G1T/Abf/Fbf only

  prep<<<dim3(4480), 256, 0, stream>>>(feat, E, wp, bp, Fbf, FbfT, Abf, Bias, Wg);
  gemm128<1><<<dim3(32, 16), 256, 0, stream>>>(Abf, FbfT, G1, G1T, nullptr);
  gemm128<2><<<dim3(32, 16), 256, 0, stream>>>(Abf, G1T, G2, nullptr, Fbf);
  final_gemm<<<dim3(2048), 256, 0, stream>>>(Fbf, G1, G2, Wg, Bias, out);
}

// Round 3
// 219.520 us; speedup vs baseline: 1.1687x; 1.0920x over previous
//
#include <hip/hip_runtime.h>
#include <stdint.h>

// Problem constants (fixed by the reference)
#define NN 2048      // nodes
#define DE 16        // embedding dim
#define BB 64        // batch
#define CC 64        // in channels
#define OO 64        // out channels
#define BC 4096      // BB*CC
#define KR 192       // K*CC = 3*64 reduction length
#define JJ 12288     // KR*OO

using bf16x8 = __attribute__((ext_vector_type(8))) __bf16;
using f32x4  = __attribute__((ext_vector_type(4))) float;

__device__ __forceinline__ unsigned short f2bf(float f) {
  union { float f; unsigned int u; } v; v.f = f;
  unsigned int u = v.u;
  return (unsigned short)((u + 0x7FFFu + ((u >> 16) & 1u)) >> 16);  // RNE
}
__device__ __forceinline__ float bf2f(unsigned short h) {
  union { unsigned int u; float f; } v; v.u = ((unsigned int)h) << 16;
  return v.f;
}
// async global->LDS, 16B per lane. LDS dst is wave-uniform base + lane*16.
__device__ __forceinline__ void gll16(const void* g, void* l) {
  __builtin_amdgcn_global_load_lds(
      (const __attribute__((address_space(1))) unsigned int*)g,
      (__attribute__((address_space(3))) unsigned int*)l, 16, 0, 0);
}

// ---------------------------------------------------------------------------
// Kernel 1 ("prep"): independent preprocessing merged into one dispatch.
//   blocks [0,2048):    pack feat [B,N,C] fp32 -> Fbf [N][B*C] bf16 + FbfT [B*C][N]
//   blocks [2048,4096): adjacency row softmax(relu(E E^T)) -> Abf; Bias = E@bp;
//                       also Ebf[n][16] bf16 (A-operand of make_w_mfma)
//   blocks [4096,4120): permute wp fp32 -> wpT2[j][16] bf16, j = rq*512+o*8+rl
//                       (B-operand of make_w_mfma, K8-block j-order)
__global__ __launch_bounds__(256) void prep(const float* __restrict__ feat,
                                            const float* __restrict__ E,
                                            const float* __restrict__ wp,
                                            const float* __restrict__ bp,
                                            unsigned short* __restrict__ Fbf,
                                            unsigned short* __restrict__ FbfT,
                                            unsigned short* __restrict__ Abf,
                                            float* __restrict__ Bias,
                                            unsigned short* __restrict__ Ebf,
                                            unsigned short* __restrict__ wpT2) {
  __shared__ float smem[64 * 65];  // 16.6 KB, reused per branch
  const int id = blockIdx.x;
  const int t  = threadIdx.x;

  if (id < 2048) {
    // ---- pack_feat: b = id>>5, n-tile = (id&31)*64 ----
    float (*tile)[65] = (float (*)[65])smem;  // +1 pad: conflict-free col reads
    const int b  = id >> 5;
    const int n0 = (id & 31) * 64;
    const int tr = t >> 4, tc4 = (t & 15) * 4;
#pragma unroll
    for (int i = 0; i < 4; ++i) {
      const int r = tr + i * 16;
      const float4 v = *(const float4*)(feat + (size_t)b * (NN * CC) + (size_t)(n0 + r) * CC + tc4);
      tile[r][tc4 + 0] = v.x; tile[r][tc4 + 1] = v.y;
      tile[r][tc4 + 2] = v.z; tile[r][tc4 + 3] = v.w;
    }
    __syncthreads();
#pragma unroll
    for (int i = 0; i < 4; ++i) {
      const int r = tr + i * 16;
      const unsigned int lo = f2bf(tile[r][tc4 + 0]) | ((unsigned int)f2bf(tile[r][tc4 + 1]) << 16);
      const unsigned int hi = f2bf(tile[r][tc4 + 2]) | ((unsigned int)f2bf(tile[r][tc4 + 3]) << 16);
      *(uint2*)(Fbf + (size_t)(n0 + r) * BC + b * CC + tc4) = make_uint2(lo, hi);
    }
    const int rr = t & 63;
    const int cb = t >> 6;
#pragma unroll
    for (int i = 0; i < 16; ++i) {
      const int c = cb * 16 + i;
      FbfT[(size_t)(b * CC + c) * NN + n0 + rr] = f2bf(tile[rr][c]);
    }
  } else if (id < 4096) {
    // ---- adj_softmax: one row per block ----
    const int n = id - 2048;
    float* en  = smem;       // [16]
    float* red = smem + 16;  // [8]
    if (t < 16) en[t] = E[n * 16 + t];
    __syncthreads();
    if (t < 16) Ebf[n * 16 + t] = f2bf(en[t]);
    float er[16];
#pragma unroll
    for (int d = 0; d < 16; ++d) er[d] = en[d];

    float v[8];
    float mx = 0.0f;  // relu floor: max >= 0 always
#pragma unroll
    for (int i = 0; i < 8; ++i) {
      const int m = t + i * 256;
      const float4* Em = (const float4*)(E + m * 16);
      const float4 a = Em[0], b = Em[1], c = Em[2], d = Em[3];
      float dot = er[0] * a.x + er[1] * a.y + er[2] * a.z + er[3] * a.w
                + er[4] * b.x + er[5] * b.y + er[6] * b.z + er[7] * b.w
                + er[8] * c.x + er[9] * c.y + er[10] * c.z + er[11] * c.w
                + er[12] * d.x + er[13] * d.y + er[14] * d.z + er[15] * d.w;
      v[i] = fmaxf(dot, 0.0f);
      mx = fmaxf(mx, v[i]);
    }
#pragma unroll
    for (int off = 32; off > 0; off >>= 1) mx = fmaxf(mx, __shfl_xor(mx, off, 64));
    const int wave = t >> 6, lane = t & 63;
    if (lane == 0) red[wave] = mx;
    __syncthreads();
    mx = fmaxf(fmaxf(red[0], red[1]), fmaxf(red[2], red[3]));
    float s = 0.0f;
#pragma unroll
    for (int i = 0; i < 8; ++i) { v[i] = __expf(v[i] - mx); s += v[i]; }
#pragma unroll
    for (int off = 32; off > 0; off >>= 1) s += __shfl_xor(s, off, 64);
    if (lane == 0) red[4 + wave] = s;
    __syncthreads();
    s = red[4] + red[5] + red[6] + red[7];
    const float inv = 1.0f / s;
#pragma unroll
    for (int i = 0; i < 8; ++i)
      Abf[(size_t)n * NN + t + i * 256] = f2bf(v[i] * inv);
    if (t < 64) {
      float bs = 0.0f;
#pragma unroll
      for (int d = 0; d < 16; ++d) bs += er[d] * bp[d * 64 + t];
      Bias[n * 64 + t] = bs;
    }
  } else {
    // ---- wp permute: block rq handles j in [rq*512, rq*512+512), all 16 d ----
    // wpT2[(rq*512 + o*8 + rl)*16 + d] = bf16(wp[d][rq*8+rl][o]); wp L2-resident (786 KB)
    const int rq = id - 4096;
    for (int p = t; p < 1024; p += 256) {
      const int e0 = p * 8;          // element offset within block's 8192-elem span
      const int d0 = e0 & 15;        // 0 or 8
      const int rem = e0 >> 4;       // o*8 + rl
      const int rl = rem & 7, o = rem >> 3;
      const int r = rq * 8 + rl;
      unsigned int w[4];
#pragma unroll
      for (int u = 0; u < 4; ++u) {
        const float f0 = wp[(size_t)(d0 + 2 * u) * JJ + r * 64 + o];
        const float f1 = wp[(size_t)(d0 + 2 * u + 1) * JJ + r * 64 + o];
        w[u] = f2bf(f0) | ((unsigned int)f2bf(f1) << 16);
      }
      *(uint4*)(wpT2 + (size_t)rq * 8192 + e0) = make_uint4(w[0], w[1], w[2], w[3]);
    }
  }
}

// ---------------------------------------------------------------------------
// Kernel 2: make_w via MFMA. Wg[n][j] = sum_d Ebf[n][d] * wpT2[j][d], with
// j = rq*512 + o*8 + rl encoding the K8-block layout directly. M=n, N=j,
// K=32 (upper 16 zero). Epilogue lanes are j-contiguous -> coalesced stores.
// Write-bound: 48 MB out, inputs tiny/L2-resident.
__global__ __launch_bounds__(256) void make_w_mfma(const unsigned short* __restrict__ Ebf,
                                                   const unsigned short* __restrict__ wpT2,
                                                   unsigned short* __restrict__ Wg) {
  __shared__ alignas(16) unsigned short As[128 * 16];  // [n][d] 4KB
  __shared__ alignas(16) unsigned short Bs[128 * 16];  // [j][d] 4KB
  const int t = threadIdx.x;
  const int bm = blockIdx.y * 128;   // n
  const int bj = blockIdx.x * 128;   // j
  gll16(Ebf  + (size_t)(bm + (t >> 1)) * 16 + (t & 1) * 8, &As[t * 8]);
  gll16(wpT2 + (size_t)(bj + (t >> 1)) * 16 + (t & 1) * 8, &Bs[t * 8]);
  __syncthreads();
  const int wave = t >> 6, lane = t & 63;
  const int wm = (wave >> 1) * 64, wj = (wave & 1) * 64;
  const int li = lane & 15, q = lane >> 4;
  const bool hiK = (q >= 2);   // k in [16,32): zero-padded
  const int qq = q & 1;
  bf16x8 vz;
#pragma unroll
  for (int i = 0; i < 8; ++i) vz[i] = (__bf16)0.0f;

  bf16x8 af[4], bfr[4];
#pragma unroll
  for (int r = 0; r < 4; ++r) {
    af[r] = *(const bf16x8*)&As[(wm + r * 16 + li) * 16 + qq * 8];
    if (hiK) af[r] = vz;
  }
#pragma unroll
  for (int c = 0; c < 4; ++c) {
    bfr[c] = *(const bf16x8*)&Bs[(wj + c * 16 + li) * 16 + qq * 8];
    if (hiK) bfr[c] = vz;
  }
  const int rowL = q * 4;
#pragma unroll
  for (int r = 0; r < 4; ++r) {
#pragma unroll
    for (int c = 0; c < 4; ++c) {
      f32x4 acc = (f32x4){0.f, 0.f, 0.f, 0.f};
      acc = __builtin_amdgcn_mfma_f32_16x16x32_bf16(af[r], bfr[c], acc, 0, 0, 0);
      const int gm = bm + wm + r * 16 + rowL;
      const int gj = bj + wj + c * 16 + li;
#pragma unroll
      for (int i = 0; i < 4; ++i)
        Wg[(size_t)(gm + i) * JJ + gj] = f2bf(acc[i]);
    }
  }
}

// ---------------------------------------------------------------------------
// Kernel 3: 128x128 bf16 MFMA GEMM with BK=64 (half the barrier drains of
// BK=32; occupancy is grid-capped at 2 blocks/CU so 32KB LDS is free).
// C = A[2048,2048] @ B with B given K-contiguous (Bt[j][k]). LDS XOR-swizzle
// phys = logical ^ ((row>>1)&7) -> fragment b128 reads hit 32 banks x 2 lanes.
// EPI=1: store G1 node-major + G1T transposed. EPI=2: store G2 = 2*acc - F.
template <int EPI>
__global__ __launch_bounds__(256, 2) void gemm128(const unsigned short* __restrict__ A,
                                                  const unsigned short* __restrict__ Bt,
                                                  unsigned short* __restrict__ Cnm,
                                                  unsigned short* __restrict__ Ct,
                                                  const unsigned short* __restrict__ F) {
  __shared__ alignas(16) unsigned short As[128 * 64];  // 16KB
  __shared__ alignas(16) unsigned short Bs[128 * 64];  // 16KB
  const int t = threadIdx.x;
  const int bm = blockIdx.y * 128, bn = blockIdx.x * 128;
  const int wave = t >> 6, lane = t & 63;
  const int wm = (wave >> 1) * 64, wn = (wave & 1) * 64;

  f32x4 acc[4][4];
#pragma unroll
  for (int r = 0; r < 4; ++r)
#pragma unroll
    for (int c = 0; c < 4; ++c) acc[r][c] = (f32x4){0.f, 0.f, 0.f, 0.f};

  // staging: 1024 16B-chunks per buffer; thread t fills chunks t+256i, i=0..3.
  // chunk c: row = c>>3, pos = c&7; phys pos holds logical pos ^ ((row>>1)&7).
  const int srow = t >> 3;                                 // rows srow + 32i
  const int csw = (((t & 7) ^ ((t >> 4) & 7)) * 8);        // swizzled col (elems); same for all i
  const unsigned short* Ap[4];
  const unsigned short* Bp[4];
#pragma unroll
  for (int i = 0; i < 4; ++i) {
    Ap[i] = A  + (size_t)(bm + srow + i * 32) * NN + csw;
    Bp[i] = Bt + (size_t)(bn + srow + i * 32) * NN + csw;
  }
  // fragment reads: logical chunk (kk*4+q) lives at phys ^ ((li>>1)&7)
  const int li = lane & 15, q = lane >> 4, sw = (li >> 1) & 7;
  const int arow = (wm + li) * 64, brow = (wn + li) * 64;

  for (int k0 = 0; k0 < NN; k0 += 64) {
    __syncthreads();  // prior-iter LDS reads done before overwrite
#pragma unroll
    for (int i = 0; i < 4; ++i) gll16(Ap[i] + k0, &As[(t + i * 256) * 8]);
#pragma unroll
    for (int i = 0; i < 4; ++i) gll16(Bp[i] + k0, &Bs[(t + i * 256) * 8]);
    __syncthreads();  // compiler drains vmcnt before s_barrier
#pragma unroll
    for (int kk = 0; kk < 2; ++kk) {
      bf16x8 af[4], bfr[4];
#pragma unroll
      for (int r = 0; r < 4; ++r)
        af[r] = *(const bf16x8*)&As[arow + r * 16 * 64 + (((kk * 4 + q) ^ sw) * 8)];
#pragma unroll
      for (int c = 0; c < 4; ++c)
        bfr[c] = *(const bf16x8*)&Bs[brow + c * 16 * 64 + (((kk * 4 + q) ^ sw) * 8)];
#pragma unroll
      for (int r = 0; r < 4; ++r)
#pragma unroll
        for (int c = 0; c < 4; ++c)
          acc[r][c] = __builtin_amdgcn_mfma_f32_16x16x32_bf16(af[r], bfr[c], acc[r][c], 0, 0, 0);
    }
  }

  const int colL = lane & 15, rowL = (lane >> 4) * 4;  // C/D: col=lane&15, row=quad*4+i
#pragma unroll
  for (int r = 0; r < 4; ++r) {
#pragma unroll
    for (int c = 0; c < 4; ++c) {
      const int gm = bm + wm + r * 16 + rowL;
      const int gn = bn + wn + c * 16 + colL;
      const f32x4 a = acc[r][c];
      if (EPI == 1) {
#pragma unroll
        for (int i = 0; i < 4; ++i)
          Cnm[(size_t)(gm + i) * BC + gn] = f2bf(a[i]);
        const unsigned int lo = f2bf(a[0]) | ((unsigned int)f2bf(a[1]) << 16);
        const unsigned int hi = f2bf(a[2]) | ((unsigned int)f2bf(a[3]) << 16);
        *(uint2*)(Ct + (size_t)gn * NN + gm) = make_uint2(lo, hi);  // gm%4==0 -> 8B aligned
      } else {
#pragma unroll
        for (int i = 0; i < 4; ++i) {
          const float g = 2.0f * a[i] - bf2f(F[(size_t)(gm + i) * BC + gn]);
          Cnm[(size_t)(gm + i) * BC + gn] = f2bf(g);
        }
      }
    }
  }
}

// ---------------------------------------------------------------------------
// Kernel 4: per-node GEMM out[b,n,o] = X_n[64,192] @ W_n[192,64] + bias[n,o]
// X_n rows: [F | G1 | G2] at node n. One block per node, 4 waves, 16x16x32 MFMA.
__global__ __launch_bounds__(256) void final_gemm(const unsigned short* __restrict__ Fbf,
                                                  const unsigned short* __restrict__ G1,
                                                  const unsigned short* __restrict__ G2,
                                                  const unsigned short* __restrict__ Wg,
                                                  const float* __restrict__ Bias,
                                                  float* __restrict__ out) {
  __shared__ alignas(16) unsigned short Xl[64 * 200];  // stride 200: 2-way (free) conflicts
  __shared__ alignas(16) unsigned short Wl[KR * OO];   // K8-blocked, linear copy
  const int n = blockIdx.x, t = threadIdx.x;
  const unsigned short* srcs[3] = {Fbf + (size_t)n * BC, G1 + (size_t)n * BC, G2 + (size_t)n * BC};
#pragma unroll
  for (int kk = 0; kk < 3; ++kk) {
    const uint4* s = (const uint4*)srcs[kk];
    for (int p = t; p < 512; p += 256) {
      const uint4 v = s[p];
      const int j = p * 8, b = j >> 6, i = j & 63;
      *(uint4*)&Xl[b * 200 + kk * 64 + i] = v;
    }
  }
  {
    const uint4* s = (const uint4*)(Wg + (size_t)n * JJ);
    uint4* d = (uint4*)Wl;
    for (int p = t; p < 1536; p += 256) d[p] = s[p];
  }
  __syncthreads();

  const int wave = t >> 6, lane = t & 63;
  const int q = lane >> 4;
  const int brow = wave * 16 + (lane & 15);
  f32x4 acc[4];
#pragma unroll
  for (int c = 0; c < 4; ++c) acc[c] = (f32x4){0.f, 0.f, 0.f, 0.f};
#pragma unroll
  for (int kq = 0; kq < 6; ++kq) {
    const bf16x8 a = *(const bf16x8*)&Xl[brow * 200 + kq * 32 + q * 8];
#pragma unroll
    for (int c = 0; c < 4; ++c) {
      const bf16x8 b = *(const bf16x8*)&Wl[(kq * 4 + q) * 512 + (c * 16 + (lane & 15)) * 8];
      acc[c] = __builtin_amdgcn_mfma_f32_16x16x32_bf16(a, b, acc[c], 0, 0, 0);
    }
  }
  const int col = lane & 15, rbase = wave * 16 + q * 4;
#pragma unroll
  for (int c = 0; c < 4; ++c) {
    const int o = c * 16 + col;
    const float bs = Bias[n * 64 + o];
#pragma unroll
    for (int i = 0; i < 4; ++i)
      out[(size_t)(rbase + i) * (NN * OO) + (size_t)n * OO + o] = acc[c][i] + bs;
  }
}

// ---------------------------------------------------------------------------
extern "C" void kernel_launch(void* const* d_in, const int* in_sizes, int n_in,
                              void* d_out, int out_size, void* d_ws, size_t ws_size,
                              hipStream_t stream) {
  const float* E    = (const float*)d_in[0];  // [2048,16]
  const float* feat = (const float*)d_in[1];  // [64,2048,64]
  const float* wp   = (const float*)d_in[2];  // [16,3,64,64]
  const float* bp   = (const float*)d_in[3];  // [16,64]
  float* out = (float*)d_out;

  char* ws = (char*)d_ws;
  size_t off = 0;
  auto alloc = [&](size_t bytes) -> void* {
    void* p = ws + off;
    off += (bytes + 255) & ~(size_t)255;
    return p;
  };
  unsigned short* Abf  = (unsigned short*)alloc((size_t)NN * NN * 2);   //  8 MB
  unsigned short* FbfT = (unsigned short*)alloc((size_t)BC * NN * 2);   // 16 MB (reused as G2)
  unsigned short* Fbf  = (unsigned short*)alloc((size_t)NN * BC * 2);   // 16 MB
  unsigned short* G1   = (unsigned short*)alloc((size_t)NN * BC * 2);   // 16 MB
  unsigned short* G1T  = (unsigned short*)alloc((size_t)BC * NN * 2);   // 16 MB
  unsigned short* Wg   = (unsigned short*)alloc((size_t)NN * JJ * 2);   // 48 MB
  float* Bias          = (float*)alloc((size_t)NN * OO * 4);            // 0.5 MB
  unsigned short* Ebf  = (unsigned short*)alloc((size_t)NN * DE * 2);   // 64 KB
  unsigned short* wpT2 = (unsigned short*)alloc((size_t)JJ * DE * 2);   // 384 KB
  unsigned short* G2   = FbfT;  // FbfT dead after GEMM1; GEMM2 reads G1T/Abf/Fbf only

  prep<<<dim3(4120), 256, 0, stream>>>(feat, E, wp, bp, Fbf, FbfT, Abf, Bias, Ebf, wpT2);
  make_w_mfma<<<dim3(96, 16), 256, 0, stream>>>(Ebf, wpT2, Wg);
  gemm128<1><<<dim3(32, 16), 256, 0, stream>>>(Abf, FbfT, G1, G1T, nullptr);
  gemm128<2><<<dim3(32, 16), 256, 0, stream>>>(Abf, G1T, G2, nullptr, Fbf);
  final_gemm<<<dim3(2048), 256, 0, stream>>>(Fbf, G1, G2, Wg, Bias, out);
}